// Round 8
// baseline (150.941 us; speedup 1.0000x reference)
//
#include <hip/hip_runtime.h>
#include <stdint.h>

#define NROWS 1024
#define NCOLS 16384
#define NRB 64        // row tiles (16 rows each)
#define NCB 16        // col tiles (1024 cols each)
#define TROWS 16      // rows per tile
#define NROUNDS 2
#define NBLK (NRB * NCB)   // 1024 blocks = 4/CU x 256 CU, all co-resident:
                           // launch_bounds(256,4) + small LDS -> 4 blocks/CU,
                           // plain launch (graph-capturable, round-4 verified).

#define NLEAF 64
#define LEAFSZ (NBLK / NLEAF)   // 16 arrivals per leaf

typedef unsigned long long u64;
typedef unsigned int u32;

// Persistent device state. g_colbest/g_rowmax are atomic-max targets: zeroed
// at module load for call 1, re-zeroed at the END of each call (after the
// last barrier, when their only reader - commit - is long done) for call N+1.
// All keys from real float data are > 0 (fsort(x) >= 0x00800000 for finite x),
// so zero always loses the max.
__device__ u64 g_colbest[NCOLS];               // global col maxima (atomic max)
__device__ u64 g_rowmax[NROWS];                // global row maxima (atomic max)
__device__ u64 g_rowbest[NROWS];               // rounds/finish cache of row best
__device__ int g_col_used[NCOLS];
__device__ int g_row_assigned[NROWS];
__device__ int g_rem[2][NROWS];                // double-buffered remaining lists
__device__ int g_cnt[NROUNDS + 1];             // list counts per round

// Monotone (never-reset) tree-barrier counters; valid across launches/replays.
// ROUND-4/5/7 PROVEN layout - untouched this round (one structural change at
// a time; this round's change is the atomic-max reduction).
__device__ int g_bar_leaf[NLEAF * 32];         // arrival counters, 128B/leaf
__device__ int g_bar_root;
__device__ int g_bar_gen;

// ---- RELAXED agent-scope accessors: device-coherent via MALL, NO cache
// maintenance ops (round-3 confirmed: removing wbl2/inv storms = 885->82us).
__device__ __forceinline__ u64 ald64(const u64* p) {
    return __hip_atomic_load((u64*)p, __ATOMIC_RELAXED, __HIP_MEMORY_SCOPE_AGENT);
}
__device__ __forceinline__ void ast64(u64* p, u64 v) {
    __hip_atomic_store(p, v, __ATOMIC_RELAXED, __HIP_MEMORY_SCOPE_AGENT);
}
__device__ __forceinline__ void amax64(u64* p, u64 v) {
    (void)__hip_atomic_fetch_max(p, v, __ATOMIC_RELAXED, __HIP_MEMORY_SCOPE_AGENT);
}
__device__ __forceinline__ int ald32(const int* p) {
    return __hip_atomic_load((int*)p, __ATOMIC_RELAXED, __HIP_MEMORY_SCOPE_AGENT);
}
__device__ __forceinline__ void ast32(int* p, int v) {
    __hip_atomic_store(p, v, __ATOMIC_RELAXED, __HIP_MEMORY_SCOPE_AGENT);
}
__device__ __forceinline__ int aadd32(int* p, int v) {
    return __hip_atomic_fetch_add(p, v, __ATOMIC_RELAXED, __HIP_MEMORY_SCOPE_AGENT);
}

// Fence-free grid barrier (round-4/5/7 proven, 4.8us measured). All threads
// drain vmem (stores AND fire-and-forget atomics are vmcnt-tracked, acked at
// MALL) -> syncthreads -> tid0 arrives via monotone leaf->root->gen counters.
__device__ __forceinline__ void grid_barrier(int bid, int tid) {
    asm volatile("s_waitcnt vmcnt(0)" ::: "memory");   // all threads drain
    __syncthreads();
    if (tid == 0) {
        int gen = ald32(&g_bar_gen);
        asm volatile("s_waitcnt vmcnt(0)" ::: "memory");  // snapshot bound
        int leaf = (bid & (NLEAF - 1)) * 32;
        int v = aadd32(&g_bar_leaf[leaf], 1);
        if ((v & (LEAFSZ - 1)) == LEAFSZ - 1) {           // leaf complete
            int u = aadd32(&g_bar_root, 1);
            if ((u & (NLEAF - 1)) == NLEAF - 1) {         // grid complete
                aadd32(&g_bar_gen, 1);
            }
        }
        while (ald32(&g_bar_gen) == gen) {
            __builtin_amdgcn_s_sleep(8);   // ~512cy nap, no cache ops
        }
    }
    __syncthreads();
    asm volatile("" ::: "memory");
}

// Monotone float32 -> uint32 mapping (preserves <):
__device__ __forceinline__ u32 fsort(float x) {
    u32 u = __float_as_uint(x);
    return u ^ ((u32)((int)u >> 31) | 0x80000000u);
}

__device__ __forceinline__ u64 wave_reduce_max(u64 v) {
    for (int off = 32; off; off >>= 1) {
        u64 o = __shfl_down(v, off);
        if (o > v) v = o;
    }
    return v;   // valid in lane 0
}

// blockDim == 256 (4 waves)
__device__ __forceinline__ u64 block_reduce_max(u64 v, u64* s_part) {
    v = wave_reduce_max(v);
    int wave = threadIdx.x >> 6;
    if ((threadIdx.x & 63) == 0) s_part[wave] = v;
    __syncthreads();
    u64 b = s_part[0];
    for (int w = 1; w < 4; w++) if (s_part[w] > b) b = s_part[w];
    __syncthreads();
    return b;
}

// Per-row scan helper: fold 4 cols into col-maxima (b0..b3, keyed by row) and
// produce the row-max candidate m (keyed by col).
__device__ __forceinline__ void scan_row(float4 v, int r, int c0,
                                         u64& b0, u64& b1, u64& b2, u64& b3,
                                         u64& m) {
    u32 rk = (u32)(NROWS - 1 - r);
    u64 k0 = ((u64)fsort(v.x) << 32) | rk; if (k0 > b0) b0 = k0;
    u64 k1 = ((u64)fsort(v.y) << 32) | rk; if (k1 > b1) b1 = k1;
    u64 k2 = ((u64)fsort(v.z) << 32) | rk; if (k2 > b2) b2 = k2;
    u64 k3 = ((u64)fsort(v.w) << 32) | rk; if (k3 > b3) b3 = k3;
    u64 m0 = ((u64)fsort(v.x) << 32) | (u32)(NCOLS - 1 - (c0 + 0));
    u64 m1 = ((u64)fsort(v.y) << 32) | (u32)(NCOLS - 1 - (c0 + 1));
    u64 m2 = ((u64)fsort(v.z) << 32) | (u32)(NCOLS - 1 - (c0 + 2));
    u64 m3 = ((u64)fsort(v.w) << 32) | (u32)(NCOLS - 1 - (c0 + 3));
    m = m0; if (m1 > m) m = m1; if (m2 > m) m = m2; if (m3 > m) m = m3;
}

// ---------- Phase 1: tile scan. 16 rows x 1024 cols per block ----------
// Row-max via LDS transpose reduce (round-7 banked: 24.5 -> ~13.5us).
// Col/row partials now go through ATOMIC MAX directly into g_colbest /
// g_rowmax instead of an 8MB colpart buffer: round-7 counters showed
// WRITE_SIZE 33.4MB vs 8.6MB logical = 1M 8B agent stores costing a 32B
// sector each. The atomic-max RMWs dirty only 128KB at MALL, and commit
// shrinks from an 80K-load gather burst to 2 loads per row. Monotone key
// encoding makes max produce bit-identical winners (val desc, smaller idx).
__device__ __forceinline__ void phase_scan(const float* __restrict__ cost,
                                           int fb, int tid,
                                           u64 (*s_cand)[257],
                                           u64 (*s_p2)[17]) {
    const int cb = fb & (NCB - 1);
    const int rb = fb >> 4;
    const int cbase = cb * 1024;
    const int r0 = rb * TROWS;
    const int c0 = cbase + tid * 4;

    if (rb == 0) {     // init: each cb-block zeroes its col_used slice (MALL)
        ast64((u64*)(g_col_used + cbase) + tid * 2 + 0, 0ULL);
        ast64((u64*)(g_col_used + cbase) + tid * 2 + 1, 0ULL);
        if (cb == 0 && tid <= NROUNDS) ast32(&g_cnt[tid], 0);
    }

    u64 b0 = 0, b1 = 0, b2 = 0, b3 = 0;
    for (int half = 0; half < 2; ++half) {
        const int rbase = r0 + half * 8;
        for (int g = 0; g < 8; g += 4) {
            const float* base = cost + (size_t)(rbase + g) * NCOLS + c0;
            float4 v0 = *(const float4*)(base);
            float4 v1 = *(const float4*)(base + NCOLS);
            float4 v2 = *(const float4*)(base + 2 * NCOLS);
            float4 v3 = *(const float4*)(base + 3 * NCOLS);
            u64 m0, m1, m2, m3;
            scan_row(v0, rbase + g + 0, c0, b0, b1, b2, b3, m0);
            scan_row(v1, rbase + g + 1, c0, b0, b1, b2, b3, m1);
            scan_row(v2, rbase + g + 2, c0, b0, b1, b2, b3, m2);
            scan_row(v3, rbase + g + 3, c0, b0, b1, b2, b3, m3);
            s_cand[g + 0][tid] = m0;
            s_cand[g + 1][tid] = m1;
            s_cand[g + 2][tid] = m2;
            s_cand[g + 3][tid] = m3;
        }
        __syncthreads();
        if (tid < 128) {   // stage 1: 16 threads/row, stride-16 chains
            // [257] pad: bank = 2*((r+j) mod 16) -> 4 lanes/bank-pair = the
            // b64 full-wave floor (was 8-way unpadded).
            int r = tid >> 4, j = tid & 15;
            u64 m = s_cand[r][j];
            #pragma unroll
            for (int i = 1; i < 16; i++) {
                u64 o = s_cand[r][j + 16 * i];
                if (o > m) m = o;
            }
            s_p2[half * 8 + r][j] = m;
        }
        __syncthreads();   // protects s_cand reuse (half 1) and s_p2 for stage 2
    }
    // col maxima: 4 fire-and-forget atomic max per thread (1M total, 64/line)
    amax64(&g_colbest[c0 + 0], b0);
    amax64(&g_colbest[c0 + 1], b1);
    amax64(&g_colbest[c0 + 2], b2);
    amax64(&g_colbest[c0 + 3], b3);
    if (tid < TROWS) {   // stage 2: one thread per row -> atomic row max
        u64 m = s_p2[tid][0];
        #pragma unroll
        for (int i = 1; i < 16; i++) {
            u64 o = s_p2[tid][i];
            if (o > m) m = o;
        }
        amax64(&g_rowmax[r0 + tid], m);
    }
}

// ---------- Phase 2: mutual-best commit. Block r, tid 0: 2 MALL loads ----
__device__ __forceinline__ void phase_commit(int* __restrict__ out, int r) {
    u64 key = ald64(&g_rowmax[r]);              // global row max (atomics done)
    int c = NCOLS - 1 - (int)(key & 0xFFFFFFFFu);
    u64 colmax = ald64(&g_colbest[c]);          // global col max

    ast64(&g_rowbest[r], key);                  // cache for rounds/finish
    out[r] = r;                                 // identity row indices
    u64 mk = (key & 0xFFFFFFFF00000000ULL) | (u32)(NROWS - 1 - r);
    if (colmax == mk) {                         // mutual best -> commit
        ast32(&g_col_used[c], 1);
        ast32(&g_row_assigned[r], 1);
        out[NROWS + r] = c;
    } else {
        ast32(&g_row_assigned[r], 0);
        int p = aadd32(&g_cnt[0], 1);
        ast32(&g_rem[0][p], r);
    }
}

// ---------- Per-round phase (256 threads, block = row r) ----------
__device__ __forceinline__ void phase_round(const float* __restrict__ cost,
                                            int* __restrict__ out, int t, int r,
                                            int tid, u64* s_part) {
    if (ald32(&g_row_assigned[r])) return;   // uniform across block

    u64 key = ald64(&g_rowbest[r]);
    int c = NCOLS - 1 - (int)(key & 0xFFFFFFFFu);
    if (ald32(&g_col_used[c])) {      // stale -> rescan excluding used cols
        u64 best = 0ULL;
        const float4* row = (const float4*)(cost + (size_t)r * NCOLS);
        const u64* used = (const u64*)g_col_used;
        for (int k = tid; k < NCOLS / 4; k += 256) {
            float4 v = row[k];
            u64 w0 = ald64(&used[k * 2 + 0]);   // cols c0, c0+1
            u64 w1 = ald64(&used[k * 2 + 1]);   // cols c0+2, c0+3
            int c0 = k * 4;
            if (!(u32)w0)         { u64 kk = ((u64)fsort(v.x) << 32) | (u32)(NCOLS - 1 - (c0 + 0)); if (kk > best) best = kk; }
            if (!(u32)(w0 >> 32)) { u64 kk = ((u64)fsort(v.y) << 32) | (u32)(NCOLS - 1 - (c0 + 1)); if (kk > best) best = kk; }
            if (!(u32)w1)         { u64 kk = ((u64)fsort(v.z) << 32) | (u32)(NCOLS - 1 - (c0 + 2)); if (kk > best) best = kk; }
            if (!(u32)(w1 >> 32)) { u64 kk = ((u64)fsort(v.w) << 32) | (u32)(NCOLS - 1 - (c0 + 3)); if (kk > best) best = kk; }
        }
        key = block_reduce_max(best, s_part);
        if (tid == 0) ast64(&g_rowbest[r], key);
        c = NCOLS - 1 - (int)(key & 0xFFFFFFFFu);
    }

    int n = ald32(&g_cnt[t]);
    const int* list = g_rem[t & 1];
    u64 mine = (key & 0xFFFFFFFF00000000ULL) | (u32)(NROWS - 1 - r);
    u64 mx = 0ULL;
    for (int j = tid; j < n; j += 256) {
        int rj = ald32(&list[j]);
        if (rj != r) {
            float x = cost[(size_t)rj * NCOLS + c];
            u64 kj = ((u64)fsort(x) << 32) | (u32)(NROWS - 1 - rj);
            if (kj > mx) mx = kj;
        }
    }
    mx = block_reduce_max(mx, s_part);
    if (tid == 0) {
        if (mine > mx) {              // unique max at col c among survivors
            ast32(&g_col_used[c], 1);
            ast32(&g_row_assigned[r], 1);
            out[NROWS + r] = c;
        } else {
            int p = aadd32(&g_cnt[t + 1], 1);
            ast32(&g_rem[(t + 1) & 1][p], r);
        }
    }
}

// ---------- Final serial cleanup, single block of 256 ----------
__device__ __forceinline__ void phase_finish(const float* __restrict__ cost,
                                             int* __restrict__ out, int tid,
                                             int (*s_rem)[NROWS], u64* s_part,
                                             int* s_nn) {
    if (tid == 0) s_nn[0] = ald32(&g_cnt[NROUNDS]);
    __syncthreads();
    int n = s_nn[0];
    if (n == 0) return;
    for (int i = tid; i < n; i += 256) s_rem[0][i] = ald32(&g_rem[NROUNDS & 1][i]);
    __syncthreads();
    int cur = 0;
    while (n > 0) {
        for (int i = 0; i < n; i++) {
            int r = s_rem[cur][i];
            u64 key = ald64(&g_rowbest[r]);
            int c = NCOLS - 1 - (int)(key & 0xFFFFFFFFu);
            if (ald32(&g_col_used[c])) {
                u64 best = 0ULL;
                const float4* row = (const float4*)(cost + (size_t)r * NCOLS);
                const u64* used = (const u64*)g_col_used;
                for (int k = tid; k < NCOLS / 4; k += 256) {
                    float4 v = row[k];
                    u64 w0 = ald64(&used[k * 2 + 0]);
                    u64 w1 = ald64(&used[k * 2 + 1]);
                    int c0 = k * 4;
                    if (!(u32)w0)         { u64 kk = ((u64)fsort(v.x) << 32) | (u32)(NCOLS - 1 - (c0 + 0)); if (kk > best) best = kk; }
                    if (!(u32)(w0 >> 32)) { u64 kk = ((u64)fsort(v.y) << 32) | (u32)(NCOLS - 1 - (c0 + 1)); if (kk > best) best = kk; }
                    if (!(u32)w1)         { u64 kk = ((u64)fsort(v.z) << 32) | (u32)(NCOLS - 1 - (c0 + 2)); if (kk > best) best = kk; }
                    if (!(u32)(w1 >> 32)) { u64 kk = ((u64)fsort(v.w) << 32) | (u32)(NCOLS - 1 - (c0 + 3)); if (kk > best) best = kk; }
                }
                u64 m = block_reduce_max(best, s_part);
                if (tid == 0) ast64(&g_rowbest[r], m);
            }
        }
        __syncthreads();
        if (tid == 0) s_nn[1] = 0;
        __syncthreads();
        for (int base = 0; base < n; base += 256) {
            bool win = false; int myr = -1, myc = -1;
            if (base + tid < n) {
                int r = s_rem[cur][base + tid];
                u64 key = ald64(&g_rowbest[r]);
                int c = NCOLS - 1 - (int)(key & 0xFFFFFFFFu);
                u64 mine = (key & 0xFFFFFFFF00000000ULL) | (u32)(NROWS - 1 - r);
                win = true;
                for (int j = 0; j < n; j++) {
                    int rj = s_rem[cur][j];
                    if (rj == r) continue;
                    float x = cost[(size_t)rj * NCOLS + c];
                    u64 kj = ((u64)fsort(x) << 32) | (u32)(NROWS - 1 - rj);
                    if (kj > mine) { win = false; break; }
                }
                myr = r; myc = c;
            }
            if (win) {
                ast32(&g_col_used[myc], 1);
                ast32(&g_row_assigned[myr], 1);
                out[NROWS + myr] = myc;
            }
            if (base + tid < n && !win) {
                int p = atomicAdd(&s_nn[1], 1);
                s_rem[cur ^ 1][p] = myr;
            }
        }
        __syncthreads();
        n = s_nn[1];
        cur ^= 1;
        __syncthreads();
    }
}

// ---------- Fused kernel: all phases, one dispatch, fence-free barriers ----
// LDS budget: s_cand 16448 + s_p2 2176 + s_part 32 + s_nn 8 = 18664 B;
// 4 x 18.7KB = 74.6KB << 160KB/CU (same regime round 7 proved; violating
// co-residency would deadlock the spin barrier). finish's s_rem aliases
// s_cand. After the last barrier, blocks 1..68 re-zero the atomic-max
// arrays for the next call (their only reader, commit, finished at barrier 3).
__global__ void __launch_bounds__(256, 4)
k_fused(const float* __restrict__ cost, int* __restrict__ out) {
    __shared__ u64 s_cand[8][257];
    __shared__ u64 s_p2[TROWS][17];
    __shared__ u64 s_part[4];
    __shared__ int s_nn[2];
    const int bid = blockIdx.x;
    const int tid = threadIdx.x;

    phase_scan(cost, bid, tid, s_cand, s_p2);
    grid_barrier(bid, tid);

    if (tid == 0) phase_commit(out, bid);
    grid_barrier(bid, tid);

    phase_round(cost, out, 0, bid, tid, s_part);
    grid_barrier(bid, tid);

    phase_round(cost, out, 1, bid, tid, s_part);
    grid_barrier(bid, tid);

    if (bid == 0) {
        phase_finish(cost, out, tid,
                     reinterpret_cast<int(*)[NROWS]>(&s_cand[0][0]),
                     s_part, s_nn);
    } else if (bid <= 64) {        // re-zero colbest for next call
        ast64(&g_colbest[(bid - 1) * 256 + tid], 0ULL);
    } else if (bid <= 68) {        // re-zero rowmax for next call
        ast64(&g_rowmax[(bid - 65) * 256 + tid], 0ULL);
    }
}

extern "C" void kernel_launch(void* const* d_in, const int* in_sizes, int n_in,
                              void* d_out, int out_size, void* d_ws, size_t ws_size,
                              hipStream_t stream) {
    const float* cost = (const float*)d_in[0];
    int* out = (int*)d_out;
    k_fused<<<dim3(NBLK), dim3(256), 0, stream>>>(cost, out);
}

// Round 9
// 127.782 us; speedup vs baseline: 1.1812x; 1.1812x over previous
//
#include <hip/hip_runtime.h>
#include <stdint.h>

#define NROWS 1024
#define NCOLS 16384
#define NRB 64        // row tiles (16 rows each)
#define NCB 16        // col tiles (1024 cols each)
#define TROWS 16      // rows per tile
#define NROUNDS 2
#define NBLK (NRB * NCB)   // 1024 blocks = 4/CU x 256 CU, all co-resident:
                           // launch_bounds(256,4) + small LDS -> 4 blocks/CU,
                           // plain launch (graph-capturable, round-4 verified).

#define NLEAF 64
#define LEAFSZ (NBLK / NLEAF)   // 16 arrivals per leaf

typedef unsigned long long u64;
typedef unsigned int u32;

// Persistent device state (round-7 proven layout: colpart buffer is BACK —
// round-8's atomic-max replacement regressed 70->81us, WRITE_SIZE unchanged:
// 1M MALL RMWs are slower than 1M fire-and-forget stores, and the write
// traffic is op-count-driven either way).
__device__ u64 g_rowpart[NCB * NROWS];         // per col-tile row maxima
__device__ u64 g_colpart[(size_t)NRB * NCOLS]; // per row-tile col maxima (8 MB)
__device__ u64 g_rowbest[NROWS];               // key: (sortable<<32)|(NCOLS-1-col)
__device__ int g_col_used[NCOLS];
__device__ int g_row_assigned[NROWS];
__device__ int g_rem[2][NROWS];                // double-buffered remaining lists
__device__ int g_cnt[NROUNDS + 1];             // list counts per round

// Monotone (never-reset) tree-barrier counters; valid across launches/replays.
// g_bar_lgen (broadcast release lines) and g_bar_gen (proven backstop line)
// advance in lockstep, 1 per barrier.
__device__ int g_bar_leaf[NLEAF * 32];         // arrival counters, 128B/leaf
__device__ int g_bar_root;
__device__ int g_bar_lgen[NLEAF * 32];         // per-leaf release gen lines
__device__ int g_bar_gen;                      // backstop release line (proven)

// ---- RELAXED agent-scope accessors: device-coherent via MALL, NO cache
// maintenance ops (round-3 confirmed: removing wbl2/inv storms = 885->82us).
__device__ __forceinline__ u64 ald64(const u64* p) {
    return __hip_atomic_load((u64*)p, __ATOMIC_RELAXED, __HIP_MEMORY_SCOPE_AGENT);
}
__device__ __forceinline__ void ast64(u64* p, u64 v) {
    __hip_atomic_store(p, v, __ATOMIC_RELAXED, __HIP_MEMORY_SCOPE_AGENT);
}
__device__ __forceinline__ int ald32(const int* p) {
    return __hip_atomic_load((int*)p, __ATOMIC_RELAXED, __HIP_MEMORY_SCOPE_AGENT);
}
__device__ __forceinline__ void ast32(int* p, int v) {
    __hip_atomic_store(p, v, __ATOMIC_RELAXED, __HIP_MEMORY_SCOPE_AGENT);
}
__device__ __forceinline__ int aadd32(int* p, int v) {
    return __hip_atomic_fetch_add(p, v, __ATOMIC_RELAXED, __HIP_MEMORY_SCOPE_AGENT);
}

// Grid barrier with BROADCAST release + proven backstop. Round-5 measured
// 4.8us/barrier: 1024 tid0s contention-polling ONE MALL line. Now the grid
// completer fans gen+1 out to 64 per-leaf lines (16 pollers each) and ALSO
// bumps g_bar_gen — the round-4/5/7-proven single release line — as a
// deadlock-proof backstop polled every 8th nap (round 6, which contained the
// broadcast-only variant, died unattributed; this version cannot hang even
// if the broadcast path is flawed).
// Causality: every thread drains vmcnt(0) before arrival; leaf->root adds are
// dependent MALL RMWs; release stores issue only after the root add returns,
// so observing EITHER release line implies all pre-barrier MALL stores.
__device__ __forceinline__ void grid_barrier(int bid, int tid) {
    asm volatile("s_waitcnt vmcnt(0)" ::: "memory");   // all threads drain
    __syncthreads();
    if (tid == 0) {
        const int leaf = (bid & (NLEAF - 1)) * 32;
        int gen = ald32(&g_bar_lgen[leaf]);               // lockstep snapshot
        asm volatile("s_waitcnt vmcnt(0)" ::: "memory");  // snapshot complete
        int v = aadd32(&g_bar_leaf[leaf], 1);
        if ((v & (LEAFSZ - 1)) == LEAFSZ - 1) {           // leaf complete
            int u = aadd32(&g_bar_root, 1);
            if ((u & (NLEAF - 1)) == NLEAF - 1) {         // grid complete
                #pragma unroll
                for (int l = 0; l < NLEAF; l++)           // broadcast release
                    ast32(&g_bar_lgen[l * 32], gen + 1);
                aadd32(&g_bar_gen, 1);                    // backstop release
            }
        }
        int spins = 0;
        while (ald32(&g_bar_lgen[leaf]) == gen) {
            __builtin_amdgcn_s_sleep(2);   // ~128cy nap, 16 pollers/line
            if ((++spins & 7) == 0 && ald32(&g_bar_gen) != gen) break;
        }
    }
    __syncthreads();
    asm volatile("" ::: "memory");
}

// Monotone float32 -> uint32 mapping (preserves <):
__device__ __forceinline__ u32 fsort(float x) {
    u32 u = __float_as_uint(x);
    return u ^ ((u32)((int)u >> 31) | 0x80000000u);
}

__device__ __forceinline__ u64 wave_reduce_max(u64 v) {
    for (int off = 32; off; off >>= 1) {
        u64 o = __shfl_down(v, off);
        if (o > v) v = o;
    }
    return v;   // valid in lane 0
}

// blockDim == 256 (4 waves)
__device__ __forceinline__ u64 block_reduce_max(u64 v, u64* s_part) {
    v = wave_reduce_max(v);
    int wave = threadIdx.x >> 6;
    if ((threadIdx.x & 63) == 0) s_part[wave] = v;
    __syncthreads();
    u64 b = s_part[0];
    for (int w = 1; w < 4; w++) if (s_part[w] > b) b = s_part[w];
    __syncthreads();
    return b;
}

// Per-row scan helper: fold 4 cols into col-maxima (b0..b3, keyed by row) and
// produce the row-max candidate m (keyed by col).
__device__ __forceinline__ void scan_row(float4 v, int r, int c0,
                                         u64& b0, u64& b1, u64& b2, u64& b3,
                                         u64& m) {
    u32 rk = (u32)(NROWS - 1 - r);
    u64 k0 = ((u64)fsort(v.x) << 32) | rk; if (k0 > b0) b0 = k0;
    u64 k1 = ((u64)fsort(v.y) << 32) | rk; if (k1 > b1) b1 = k1;
    u64 k2 = ((u64)fsort(v.z) << 32) | rk; if (k2 > b2) b2 = k2;
    u64 k3 = ((u64)fsort(v.w) << 32) | rk; if (k3 > b3) b3 = k3;
    u64 m0 = ((u64)fsort(v.x) << 32) | (u32)(NCOLS - 1 - (c0 + 0));
    u64 m1 = ((u64)fsort(v.y) << 32) | (u32)(NCOLS - 1 - (c0 + 1));
    u64 m2 = ((u64)fsort(v.z) << 32) | (u32)(NCOLS - 1 - (c0 + 2));
    u64 m3 = ((u64)fsort(v.w) << 32) | (u32)(NCOLS - 1 - (c0 + 3));
    m = m0; if (m1 > m) m = m1; if (m2 > m) m = m2; if (m3 > m) m = m3;
}

// ---------- Phase 1: tile scan. 16 rows x 1024 cols per block ----------
// Row-max via LDS transpose reduce (round-7 banked: 24.5 -> ~13.5us).
// Col partials -> agent colpart stores (round-7 proven; round-8's atomic-max
// alternative was slower). Two 8-row passes through a [8][257] buffer.
__device__ __forceinline__ void phase_scan(const float* __restrict__ cost,
                                           int fb, int tid,
                                           u64 (*s_cand)[257],
                                           u64 (*s_p2)[17]) {
    const int cb = fb & (NCB - 1);
    const int rb = fb >> 4;
    const int cbase = cb * 1024;
    const int r0 = rb * TROWS;
    const int c0 = cbase + tid * 4;

    if (rb == 0) {     // init: each cb-block zeroes its col_used slice (MALL)
        ast64((u64*)(g_col_used + cbase) + tid * 2 + 0, 0ULL);
        ast64((u64*)(g_col_used + cbase) + tid * 2 + 1, 0ULL);
        if (cb == 0 && tid <= NROUNDS) ast32(&g_cnt[tid], 0);
    }

    u64 b0 = 0, b1 = 0, b2 = 0, b3 = 0;
    for (int half = 0; half < 2; ++half) {
        const int rbase = r0 + half * 8;
        for (int g = 0; g < 8; g += 4) {
            const float* base = cost + (size_t)(rbase + g) * NCOLS + c0;
            float4 v0 = *(const float4*)(base);
            float4 v1 = *(const float4*)(base + NCOLS);
            float4 v2 = *(const float4*)(base + 2 * NCOLS);
            float4 v3 = *(const float4*)(base + 3 * NCOLS);
            u64 m0, m1, m2, m3;
            scan_row(v0, rbase + g + 0, c0, b0, b1, b2, b3, m0);
            scan_row(v1, rbase + g + 1, c0, b0, b1, b2, b3, m1);
            scan_row(v2, rbase + g + 2, c0, b0, b1, b2, b3, m2);
            scan_row(v3, rbase + g + 3, c0, b0, b1, b2, b3, m3);
            s_cand[g + 0][tid] = m0;
            s_cand[g + 1][tid] = m1;
            s_cand[g + 2][tid] = m2;
            s_cand[g + 3][tid] = m3;
        }
        __syncthreads();
        if (tid < 128) {   // stage 1: 16 threads/row, stride-16 chains
            // [257] pad: consecutive j walk different bank pairs (was 8-way
            // conflicted unpadded; pad reaches the b64 full-wave floor).
            int r = tid >> 4, j = tid & 15;
            u64 m = s_cand[r][j];
            #pragma unroll
            for (int i = 1; i < 16; i++) {
                u64 o = s_cand[r][j + 16 * i];
                if (o > m) m = o;
            }
            s_p2[half * 8 + r][j] = m;
        }
        __syncthreads();   // protects s_cand reuse (half 1) and s_p2 for stage 2
    }
    size_t cp = (size_t)rb * NCOLS + c0;
    ast64(&g_colpart[cp + 0], b0);
    ast64(&g_colpart[cp + 1], b1);
    ast64(&g_colpart[cp + 2], b2);
    ast64(&g_colpart[cp + 3], b3);
    if (tid < TROWS) {   // stage 2: one thread per row
        u64 m = s_p2[tid][0];
        #pragma unroll
        for (int i = 1; i < 16; i++) {
            u64 o = s_p2[tid][i];
            if (o > m) m = o;
        }
        ast64(&g_rowpart[cb * NROWS + (r0 + tid)], m);
    }
}

// ---------- Phase 2: mutual-best commit. One wave per row r ----------
__device__ __forceinline__ void phase_commit(int* __restrict__ out, int r, int lane) {
    u64 v = ald64(&g_rowpart[(lane & 15) * NROWS + r]);
    u64 key = wave_reduce_max(v);
    key = __shfl(key, 0);                       // broadcast
    int c = NCOLS - 1 - (int)(key & 0xFFFFFFFFu);

    u64 cp = ald64(&g_colpart[(size_t)lane * NCOLS + c]);
    u64 colmax = wave_reduce_max(cp);           // lane 0

    if (lane == 0) {
        ast64(&g_rowbest[r], key);
        out[r] = r;                             // identity row indices
        u64 mk = (key & 0xFFFFFFFF00000000ULL) | (u32)(NROWS - 1 - r);
        if (colmax == mk) {                     // mutual best -> commit
            ast32(&g_col_used[c], 1);
            ast32(&g_row_assigned[r], 1);
            out[NROWS + r] = c;
        } else {
            ast32(&g_row_assigned[r], 0);
            int p = aadd32(&g_cnt[0], 1);
            ast32(&g_rem[0][p], r);
        }
    }
}

// ---------- Per-round phase (256 threads, block = row r) ----------
__device__ __forceinline__ void phase_round(const float* __restrict__ cost,
                                            int* __restrict__ out, int t, int r,
                                            int tid, u64* s_part) {
    if (ald32(&g_row_assigned[r])) return;   // uniform across block

    u64 key = ald64(&g_rowbest[r]);
    int c = NCOLS - 1 - (int)(key & 0xFFFFFFFFu);
    if (ald32(&g_col_used[c])) {      // stale -> rescan excluding used cols
        u64 best = 0ULL;
        const float4* row = (const float4*)(cost + (size_t)r * NCOLS);
        const u64* used = (const u64*)g_col_used;
        for (int k = tid; k < NCOLS / 4; k += 256) {
            float4 v = row[k];
            u64 w0 = ald64(&used[k * 2 + 0]);   // cols c0, c0+1
            u64 w1 = ald64(&used[k * 2 + 1]);   // cols c0+2, c0+3
            int c0 = k * 4;
            if (!(u32)w0)         { u64 kk = ((u64)fsort(v.x) << 32) | (u32)(NCOLS - 1 - (c0 + 0)); if (kk > best) best = kk; }
            if (!(u32)(w0 >> 32)) { u64 kk = ((u64)fsort(v.y) << 32) | (u32)(NCOLS - 1 - (c0 + 1)); if (kk > best) best = kk; }
            if (!(u32)w1)         { u64 kk = ((u64)fsort(v.z) << 32) | (u32)(NCOLS - 1 - (c0 + 2)); if (kk > best) best = kk; }
            if (!(u32)(w1 >> 32)) { u64 kk = ((u64)fsort(v.w) << 32) | (u32)(NCOLS - 1 - (c0 + 3)); if (kk > best) best = kk; }
        }
        key = block_reduce_max(best, s_part);
        if (tid == 0) ast64(&g_rowbest[r], key);
        c = NCOLS - 1 - (int)(key & 0xFFFFFFFFu);
    }

    int n = ald32(&g_cnt[t]);
    const int* list = g_rem[t & 1];
    u64 mine = (key & 0xFFFFFFFF00000000ULL) | (u32)(NROWS - 1 - r);
    u64 mx = 0ULL;
    for (int j = tid; j < n; j += 256) {
        int rj = ald32(&list[j]);
        if (rj != r) {
            float x = cost[(size_t)rj * NCOLS + c];
            u64 kj = ((u64)fsort(x) << 32) | (u32)(NROWS - 1 - rj);
            if (kj > mx) mx = kj;
        }
    }
    mx = block_reduce_max(mx, s_part);
    if (tid == 0) {
        if (mine > mx) {              // unique max at col c among survivors
            ast32(&g_col_used[c], 1);
            ast32(&g_row_assigned[r], 1);
            out[NROWS + r] = c;
        } else {
            int p = aadd32(&g_cnt[t + 1], 1);
            ast32(&g_rem[(t + 1) & 1][p], r);
        }
    }
}

// ---------- Final serial cleanup, single block of 256 ----------
__device__ __forceinline__ void phase_finish(const float* __restrict__ cost,
                                             int* __restrict__ out, int tid,
                                             int (*s_rem)[NROWS], u64* s_part,
                                             int* s_nn) {
    if (tid == 0) s_nn[0] = ald32(&g_cnt[NROUNDS]);
    __syncthreads();
    int n = s_nn[0];
    if (n == 0) return;
    for (int i = tid; i < n; i += 256) s_rem[0][i] = ald32(&g_rem[NROUNDS & 1][i]);
    __syncthreads();
    int cur = 0;
    while (n > 0) {
        for (int i = 0; i < n; i++) {
            int r = s_rem[cur][i];
            u64 key = ald64(&g_rowbest[r]);
            int c = NCOLS - 1 - (int)(key & 0xFFFFFFFFu);
            if (ald32(&g_col_used[c])) {
                u64 best = 0ULL;
                const float4* row = (const float4*)(cost + (size_t)r * NCOLS);
                const u64* used = (const u64*)g_col_used;
                for (int k = tid; k < NCOLS / 4; k += 256) {
                    float4 v = row[k];
                    u64 w0 = ald64(&used[k * 2 + 0]);
                    u64 w1 = ald64(&used[k * 2 + 1]);
                    int c0 = k * 4;
                    if (!(u32)w0)         { u64 kk = ((u64)fsort(v.x) << 32) | (u32)(NCOLS - 1 - (c0 + 0)); if (kk > best) best = kk; }
                    if (!(u32)(w0 >> 32)) { u64 kk = ((u64)fsort(v.y) << 32) | (u32)(NCOLS - 1 - (c0 + 1)); if (kk > best) best = kk; }
                    if (!(u32)w1)         { u64 kk = ((u64)fsort(v.z) << 32) | (u32)(NCOLS - 1 - (c0 + 2)); if (kk > best) best = kk; }
                    if (!(u32)(w1 >> 32)) { u64 kk = ((u64)fsort(v.w) << 32) | (u32)(NCOLS - 1 - (c0 + 3)); if (kk > best) best = kk; }
                }
                u64 m = block_reduce_max(best, s_part);
                if (tid == 0) ast64(&g_rowbest[r], m);
            }
        }
        __syncthreads();
        if (tid == 0) s_nn[1] = 0;
        __syncthreads();
        for (int base = 0; base < n; base += 256) {
            bool win = false; int myr = -1, myc = -1;
            if (base + tid < n) {
                int r = s_rem[cur][base + tid];
                u64 key = ald64(&g_rowbest[r]);
                int c = NCOLS - 1 - (int)(key & 0xFFFFFFFFu);
                u64 mine = (key & 0xFFFFFFFF00000000ULL) | (u32)(NROWS - 1 - r);
                win = true;
                for (int j = 0; j < n; j++) {
                    int rj = s_rem[cur][j];
                    if (rj == r) continue;
                    float x = cost[(size_t)rj * NCOLS + c];
                    u64 kj = ((u64)fsort(x) << 32) | (u32)(NROWS - 1 - rj);
                    if (kj > mine) { win = false; break; }
                }
                myr = r; myc = c;
            }
            if (win) {
                ast32(&g_col_used[myc], 1);
                ast32(&g_row_assigned[myr], 1);
                out[NROWS + myr] = myc;
            }
            if (base + tid < n && !win) {
                int p = atomicAdd(&s_nn[1], 1);
                s_rem[cur ^ 1][p] = myr;
            }
        }
        __syncthreads();
        n = s_nn[1];
        cur ^= 1;
        __syncthreads();
    }
}

// ---------- Fused kernel: all phases, one dispatch, fence-free barriers ----
// LDS budget: s_cand 16448 + s_p2 2176 + s_part 32 + s_nn 8 = 18664 B;
// 4 x 18.7KB = 74.6KB << 160KB/CU (regime round 7/8 proved holds 4 blocks/CU;
// violating co-residency would deadlock arrivals - though the release side is
// now hang-proof). finish's s_rem aliases s_cand.
__global__ void __launch_bounds__(256, 4)
k_fused(const float* __restrict__ cost, int* __restrict__ out) {
    __shared__ u64 s_cand[8][257];
    __shared__ u64 s_p2[TROWS][17];
    __shared__ u64 s_part[4];
    __shared__ int s_nn[2];
    const int bid = blockIdx.x;
    const int tid = threadIdx.x;

    phase_scan(cost, bid, tid, s_cand, s_p2);
    grid_barrier(bid, tid);

    if (tid < 64) phase_commit(out, bid, tid);
    grid_barrier(bid, tid);

    phase_round(cost, out, 0, bid, tid, s_part);
    grid_barrier(bid, tid);

    phase_round(cost, out, 1, bid, tid, s_part);
    grid_barrier(bid, tid);

    if (bid == 0)
        phase_finish(cost, out, tid,
                     reinterpret_cast<int(*)[NROWS]>(&s_cand[0][0]),
                     s_part, s_nn);
}

extern "C" void kernel_launch(void* const* d_in, const int* in_sizes, int n_in,
                              void* d_out, int out_size, void* d_ws, size_t ws_size,
                              hipStream_t stream) {
    const float* cost = (const float*)d_in[0];
    int* out = (int*)d_out;
    k_fused<<<dim3(NBLK), dim3(256), 0, stream>>>(cost, out);
}